// Round 4
// baseline (122.777 us; speedup 1.0000x reference)
//
#include <hip/hip_runtime.h>
#include <hip/hip_bf16.h>

typedef __bf16 bf16;
typedef __bf16 bf16x4 __attribute__((ext_vector_type(4)));
typedef __bf16 bf16x8 __attribute__((ext_vector_type(8)));
typedef float floatx4 __attribute__((ext_vector_type(4)));

#define MFMA16(A, B, C) __builtin_amdgcn_mfma_f32_16x16x32_bf16(A, B, C, 0, 0, 0)

constexpr int NQ = 4096;
constexpr int NK = 8192;
constexpr int AD = 64;            // attention dim (= Dv)
constexpr int KSPLIT = 32;        // key-dimension split (1024 blocks = 4/CU)
constexpr int BQ = 128;           // q rows per flash block (4 waves x 32)
constexpr int BK = 64;            // keys per tile
constexpr int KPB = NK / KSPLIT;  // 256 keys per block
constexpr int TILES = KPB / BK;   // 4 tiles
// 1/sqrt(64) * log2(e): scores land in log2 domain -> raw v_exp_f32
constexpr float QSCALE = 0.125f * 1.4426950408889634f;

__device__ inline bf16x8 ld_cvt8(const float* __restrict__ p) {
  float4 a = *(const float4*)p;
  float4 b = *(const float4*)(p + 4);
  bf16x8 r = {(bf16)a.x, (bf16)a.y, (bf16)a.z, (bf16)a.w,
              (bf16)b.x, (bf16)b.y, (bf16)b.z, (bf16)b.w};
  return r;
}

// ---------------- MFMA projections ------------------------------------------
// b<64: Q (64 rows each), b<192: K, else V. A = W rows [m=l16][k=quad*8+j],
// B = X rows [n=l16][k=quad*8+j], D[m=quad*4+r][n=l16].
__global__ __launch_bounds__(256) void proj_mfma(
    const float* __restrict__ q, const float* __restrict__ k,
    const float* __restrict__ v,
    const float* __restrict__ Wq, const float* __restrict__ bq,
    const float* __restrict__ Wk, const float* __restrict__ bk,
    const float* __restrict__ Wv, const float* __restrict__ bv,
    bf16* __restrict__ qout, bf16* __restrict__ kout, bf16* __restrict__ vtout) {
  const int tid = threadIdx.x;
  const int wave = tid >> 6, lane = tid & 63;
  const int l16 = lane & 15, quad = lane >> 4;
  const int b = blockIdx.x;

  if (b < 192) {  // Q or K: in-dim 128
    const bool isQ = (b < 64);
    const float* X = isQ ? q : k;
    const float* W = isQ ? Wq : Wk;
    const float* bias = isQ ? bq : bk;
    bf16* Y = isQ ? qout : kout;
    const float oscale = isQ ? QSCALE : 1.0f;
    const int rowbase = (isQ ? b : b - 64) * 64 + wave * 16;

    bf16x8 bf_[4];
#pragma unroll
    for (int ks = 0; ks < 4; ++ks)
      bf_[ks] = ld_cvt8(X + (size_t)(rowbase + l16) * 128 + ks * 32 + quad * 8);
    bf16x8 af[4][4];
#pragma unroll
    for (int mt = 0; mt < 4; ++mt)
#pragma unroll
      for (int ks = 0; ks < 4; ++ks)
        af[mt][ks] = ld_cvt8(W + (size_t)(mt * 16 + l16) * 128 + ks * 32 + quad * 8);

    floatx4 acc[4];
#pragma unroll
    for (int mt = 0; mt < 4; ++mt) acc[mt] = (floatx4){0.f, 0.f, 0.f, 0.f};
#pragma unroll
    for (int mt = 0; mt < 4; ++mt)
#pragma unroll
      for (int ks = 0; ks < 4; ++ks)
        acc[mt] = MFMA16(af[mt][ks], bf_[ks], acc[mt]);

#pragma unroll
    for (int mt = 0; mt < 4; ++mt) {
      float4 bb = *(const float4*)(bias + mt * 16 + quad * 4);
      bf16x4 o = {(bf16)((acc[mt][0] + bb.x) * oscale),
                  (bf16)((acc[mt][1] + bb.y) * oscale),
                  (bf16)((acc[mt][2] + bb.z) * oscale),
                  (bf16)((acc[mt][3] + bb.w) * oscale)};
      *(bf16x4*)(Y + (size_t)(rowbase + l16) * 64 + mt * 16 + quad * 4) = o;
    }
  } else {  // V: in-dim 64, out V^T[dv][key]
    const int keybase = (b - 192) * 64 + wave * 16;
    bf16x8 af2[2];
#pragma unroll
    for (int ks = 0; ks < 2; ++ks)
      af2[ks] = ld_cvt8(v + (size_t)(keybase + l16) * 64 + ks * 32 + quad * 8);
    bf16x8 bf2[4][2];
#pragma unroll
    for (int nt = 0; nt < 4; ++nt)
#pragma unroll
      for (int ks = 0; ks < 2; ++ks)
        bf2[nt][ks] = ld_cvt8(Wv + (size_t)(nt * 16 + l16) * 64 + ks * 32 + quad * 8);

    floatx4 acc[4];
#pragma unroll
    for (int nt = 0; nt < 4; ++nt) acc[nt] = (floatx4){0.f, 0.f, 0.f, 0.f};
#pragma unroll
    for (int nt = 0; nt < 4; ++nt)
#pragma unroll
      for (int ks = 0; ks < 2; ++ks)
        acc[nt] = MFMA16(af2[ks], bf2[nt][ks], acc[nt]);

#pragma unroll
    for (int nt = 0; nt < 4; ++nt) {
      float bvv = bv[nt * 16 + l16];
      bf16x4 o = {(bf16)(acc[nt][0] + bvv), (bf16)(acc[nt][1] + bvv),
                  (bf16)(acc[nt][2] + bvv), (bf16)(acc[nt][3] + bvv)};
      *(bf16x4*)(vtout + (size_t)(nt * 16 + l16) * NK + keybase + quad * 4) = o;
    }
  }
}

// ---------------- flash attention, barrier-free ------------------------------
// K/V fragments loaded straight from global in MFMA layout (L1/L2-served);
// only LDS use is the per-wave-private P transpose. Zero __syncthreads.
__global__ __launch_bounds__(256, 4) void flash_kernel(
    const bf16* __restrict__ qp, const bf16* __restrict__ kp,
    const bf16* __restrict__ vt, bf16* __restrict__ Opart,
    float* __restrict__ lpart) {
  __shared__ __align__(16) bf16 Pt[4][32][72];

  const int tid = threadIdx.x;
  const int wave = tid >> 6;
  const int lane = tid & 63;
  const int l16 = lane & 15;
  const int quad = lane >> 4;
  const int ks = blockIdx.x;
  const int qb = blockIdx.y;
  const int qbase = qb * BQ + wave * 32;

  bf16x8 qf[2][2];
#pragma unroll
  for (int g = 0; g < 2; ++g)
#pragma unroll
    for (int c = 0; c < 2; ++c)
      qf[g][c] = *(const bf16x8*)(qp + (size_t)(qbase + g * 16 + l16) * AD +
                                  c * 32 + quad * 8);

  floatx4 o[2][4];
#pragma unroll
  for (int g = 0; g < 2; ++g)
#pragma unroll
    for (int nt = 0; nt < 4; ++nt)
      o[g][nt] = (floatx4){0.f, 0.f, 0.f, 0.f};
  float lsum[2] = {0.f, 0.f};

  for (int kt = 0; kt < TILES; ++kt) {
    const int keybase = ks * KPB + kt * BK;

    // S^T = K.Q^T per 16-key subtile; exp + pack immediately
#pragma unroll
    for (int st = 0; st < 4; ++st) {
      const bf16* krow = kp + (size_t)(keybase + st * 16 + l16) * AD + quad * 8;
      bf16x8 ka0 = *(const bf16x8*)krow;
      bf16x8 ka1 = *(const bf16x8*)(krow + 32);
#pragma unroll
      for (int g = 0; g < 2; ++g) {
        floatx4 acc = {0.f, 0.f, 0.f, 0.f};
        acc = MFMA16(ka0, qf[g][0], acc);
        acc = MFMA16(ka1, qf[g][1], acc);
        float p0 = __builtin_amdgcn_exp2f(acc[0]);
        float p1 = __builtin_amdgcn_exp2f(acc[1]);
        float p2 = __builtin_amdgcn_exp2f(acc[2]);
        float p3 = __builtin_amdgcn_exp2f(acc[3]);
        lsum[g] += (p0 + p1) + (p2 + p3);
        bf16x4 pk = {(bf16)p0, (bf16)p1, (bf16)p2, (bf16)p3};
        *(bf16x4*)&Pt[wave][g * 16 + l16][st * 16 + quad * 4] = pk;
      }
    }
    // per-wave-private LDS: compiler-inserted lgkmcnt orders write->read

    bf16x8 pf[2][2];
#pragma unroll
    for (int g = 0; g < 2; ++g)
#pragma unroll
      for (int c = 0; c < 2; ++c)
        pf[g][c] = *(const bf16x8*)&Pt[wave][g * 16 + l16][quad * 8 + c * 32];

#pragma unroll
    for (int nt = 0; nt < 4; ++nt) {
      const bf16* vrow = vt + (size_t)(nt * 16 + l16) * NK + keybase + quad * 8;
      bf16x8 vb0 = *(const bf16x8*)vrow;
      bf16x8 vb1 = *(const bf16x8*)(vrow + 32);  // keys 32..63 of tile (FIXED)
#pragma unroll
      for (int g = 0; g < 2; ++g) {
        o[g][nt] = MFMA16(pf[g][0], vb0, o[g][nt]);
        o[g][nt] = MFMA16(pf[g][1], vb1, o[g][nt]);
      }
    }
  }

#pragma unroll
  for (int g = 0; g < 2; ++g) {
    float t = lsum[g];
    t += __shfl_xor(t, 16, 64);
    t += __shfl_xor(t, 32, 64);
    lsum[g] = t;
  }

  bf16* ob = Opart + (size_t)ks * NQ * AD + (size_t)qbase * AD;
#pragma unroll
  for (int g = 0; g < 2; ++g)
#pragma unroll
    for (int nt = 0; nt < 4; ++nt)
#pragma unroll
      for (int r = 0; r < 4; ++r)
        ob[(size_t)(g * 16 + quad * 4 + r) * AD + nt * 16 + l16] =
            (bf16)o[g][nt][r];
  if (quad == 0) {
#pragma unroll
    for (int g = 0; g < 2; ++g)
      lpart[(size_t)ks * NQ + qbase + g * 16 + l16] = lsum[g];
  }
}

// ---------------- combine partials ------------------------------------------
__global__ __launch_bounds__(256) void combine_kernel(
    const bf16* __restrict__ Opart, const float* __restrict__ lpart,
    float* __restrict__ out) {
  int t = blockIdx.x * 256 + threadIdx.x;
  int gid = t * 4;
  int qrow = gid >> 6;
  float ls = 0.f;
#pragma unroll
  for (int s = 0; s < KSPLIT; ++s) ls += lpart[(size_t)s * NQ + qrow];
  float a0 = 0.f, a1 = 0.f, a2 = 0.f, a3 = 0.f;
#pragma unroll
  for (int s = 0; s < KSPLIT; ++s) {
    bf16x4 ov = *(const bf16x4*)(Opart + (size_t)s * NQ * AD + gid);
    a0 += (float)ov[0];
    a1 += (float)ov[1];
    a2 += (float)ov[2];
    a3 += (float)ov[3];
  }
  float inv = 1.0f / ls;
  float4 res = {a0 * inv, a1 * inv, a2 * inv, a3 * inv};
  *(float4*)(out + gid) = res;
}

// ---------------- launch -----------------------------------------------------
extern "C" void kernel_launch(void* const* d_in, const int* in_sizes, int n_in,
                              void* d_out, int out_size, void* d_ws,
                              size_t ws_size, hipStream_t stream) {
  const float* q = (const float*)d_in[0];
  const float* k = (const float*)d_in[1];
  const float* v = (const float*)d_in[2];
  const float* Wq = (const float*)d_in[3];
  const float* bq = (const float*)d_in[4];
  const float* Wk = (const float*)d_in[5];
  const float* bk = (const float*)d_in[6];
  const float* Wv = (const float*)d_in[7];
  const float* bv = (const float*)d_in[8];
  float* out = (float*)d_out;

  char* ws = (char*)d_ws;
  bf16* qout = (bf16*)(ws);                    // 512 KB
  bf16* kout = (bf16*)(ws + 524288);           // 1 MB
  bf16* vtout = (bf16*)(ws + 1572864);         // 1 MB
  bf16* Opart = (bf16*)(ws + 2621440);         // 32*4096*64*2 = 32 MB
  float* lpart = (float*)(ws + 2621440 + (size_t)KSPLIT * NQ * AD * 2);

  proj_mfma<<<320, 256, 0, stream>>>(q, k, v, Wq, bq, Wk, bk, Wv, bv, qout,
                                     kout, vtout);
  flash_kernel<<<dim3(KSPLIT, NQ / BQ), 256, 0, stream>>>(qout, kout, vtout,
                                                          Opart, lpart);
  combine_kernel<<<NQ * AD / 1024, 256, 0, stream>>>(Opart, lpart, out);
}

// Round 5
// 104.558 us; speedup vs baseline: 1.1743x; 1.1743x over previous
//
#include <hip/hip_runtime.h>
#include <hip/hip_bf16.h>

typedef __bf16 bf16;
typedef __bf16 bf16x4 __attribute__((ext_vector_type(4)));
typedef __bf16 bf16x8 __attribute__((ext_vector_type(8)));
typedef float floatx4 __attribute__((ext_vector_type(4)));

#define MFMA16(A, B, C) __builtin_amdgcn_mfma_f32_16x16x32_bf16(A, B, C, 0, 0, 0)

constexpr int NQ = 4096;
constexpr int NK = 8192;
constexpr int AD = 64;            // attention dim (= Dv)
constexpr int KSPLIT = 32;        // 1024 flash blocks = 4 blocks/CU
constexpr int BQ = 128;           // q rows per flash block (4 waves x 32)
constexpr int BK = 64;            // keys per tile
constexpr int KPB = NK / KSPLIT;  // 256 keys per block
constexpr int TILES = KPB / BK;   // 4 tiles
// 1/sqrt(64) * log2(e): scores in log2 domain -> raw v_exp_f32
constexpr float QSCALE = 0.125f * 1.4426950408889634f;

__device__ inline bf16x8 ld_cvt8(const float* __restrict__ p) {
  float4 a = *(const float4*)p;
  float4 b = *(const float4*)(p + 4);
  bf16x8 r = {(bf16)a.x, (bf16)a.y, (bf16)a.z, (bf16)a.w,
              (bf16)b.x, (bf16)b.y, (bf16)b.z, (bf16)b.w};
  return r;
}

// ---------------- MFMA projections ------------------------------------------
__global__ __launch_bounds__(256) void proj_mfma(
    const float* __restrict__ q, const float* __restrict__ k,
    const float* __restrict__ v,
    const float* __restrict__ Wq, const float* __restrict__ bq,
    const float* __restrict__ Wk, const float* __restrict__ bk,
    const float* __restrict__ Wv, const float* __restrict__ bv,
    bf16* __restrict__ qout, bf16* __restrict__ kout, bf16* __restrict__ vtout) {
  const int tid = threadIdx.x;
  const int wave = tid >> 6, lane = tid & 63;
  const int l16 = lane & 15, quad = lane >> 4;
  const int b = blockIdx.x;

  if (b < 192) {  // Q or K: in-dim 128
    const bool isQ = (b < 64);
    const float* X = isQ ? q : k;
    const float* W = isQ ? Wq : Wk;
    const float* bias = isQ ? bq : bk;
    bf16* Y = isQ ? qout : kout;
    const float oscale = isQ ? QSCALE : 1.0f;
    const int rowbase = (isQ ? b : b - 64) * 64 + wave * 16;

    bf16x8 bf_[4];
#pragma unroll
    for (int ks = 0; ks < 4; ++ks)
      bf_[ks] = ld_cvt8(X + (size_t)(rowbase + l16) * 128 + ks * 32 + quad * 8);
    bf16x8 af[4][4];
#pragma unroll
    for (int mt = 0; mt < 4; ++mt)
#pragma unroll
      for (int ks = 0; ks < 4; ++ks)
        af[mt][ks] = ld_cvt8(W + (size_t)(mt * 16 + l16) * 128 + ks * 32 + quad * 8);

    floatx4 acc[4];
#pragma unroll
    for (int mt = 0; mt < 4; ++mt) acc[mt] = (floatx4){0.f, 0.f, 0.f, 0.f};
#pragma unroll
    for (int mt = 0; mt < 4; ++mt)
#pragma unroll
      for (int ks = 0; ks < 4; ++ks)
        acc[mt] = MFMA16(af[mt][ks], bf_[ks], acc[mt]);

#pragma unroll
    for (int mt = 0; mt < 4; ++mt) {
      float4 bb = *(const float4*)(bias + mt * 16 + quad * 4);
      bf16x4 o = {(bf16)((acc[mt][0] + bb.x) * oscale),
                  (bf16)((acc[mt][1] + bb.y) * oscale),
                  (bf16)((acc[mt][2] + bb.z) * oscale),
                  (bf16)((acc[mt][3] + bb.w) * oscale)};
      *(bf16x4*)(Y + (size_t)(rowbase + l16) * 64 + mt * 16 + quad * 4) = o;
    }
  } else {  // V: in-dim 64, out V^T[dv][key]
    const int keybase = (b - 192) * 64 + wave * 16;
    bf16x8 af2[2];
#pragma unroll
    for (int ks = 0; ks < 2; ++ks)
      af2[ks] = ld_cvt8(v + (size_t)(keybase + l16) * 64 + ks * 32 + quad * 8);
    bf16x8 bf2[4][2];
#pragma unroll
    for (int nt = 0; nt < 4; ++nt)
#pragma unroll
      for (int ks = 0; ks < 2; ++ks)
        bf2[nt][ks] = ld_cvt8(Wv + (size_t)(nt * 16 + l16) * 64 + ks * 32 + quad * 8);

    floatx4 acc[4];
#pragma unroll
    for (int nt = 0; nt < 4; ++nt) acc[nt] = (floatx4){0.f, 0.f, 0.f, 0.f};
#pragma unroll
    for (int nt = 0; nt < 4; ++nt)
#pragma unroll
      for (int ks = 0; ks < 2; ++ks)
        acc[nt] = MFMA16(af2[ks], bf2[nt][ks], acc[nt]);

#pragma unroll
    for (int nt = 0; nt < 4; ++nt) {
      float bvv = bv[nt * 16 + l16];
      bf16x4 o = {(bf16)(acc[nt][0] + bvv), (bf16)(acc[nt][1] + bvv),
                  (bf16)(acc[nt][2] + bvv), (bf16)(acc[nt][3] + bvv)};
      *(bf16x4*)(vtout + (size_t)(nt * 16 + l16) * NK + keybase + quad * 4) = o;
    }
  }
}

// ---------------- flash attention: LDS-staged, register-prefetched -----------
// Per tile: [barrier] ds_write prefetched regs [barrier] -> prefetch next K,
// compute S^T+exp+Pt, prefetch next V, compute PV. Global latency is covered
// by a full tile of compute. 4 blocks/CU (LDS 36.9 KB), VGPR capped at 128.
__global__ __launch_bounds__(256, 4) void flash_kernel(
    const bf16* __restrict__ qp, const bf16* __restrict__ kp,
    const bf16* __restrict__ vt, bf16* __restrict__ Opart,
    float* __restrict__ lpart) {
  __shared__ __align__(16) bf16 Kt[BK][72];
  __shared__ __align__(16) bf16 Vts[AD][72];
  __shared__ __align__(16) bf16 Pt[4][32][72];

  const int tid = threadIdx.x;
  const int wave = tid >> 6;
  const int lane = tid & 63;
  const int l16 = lane & 15;
  const int quad = lane >> 4;
  const int ks = blockIdx.x;
  const int qb = blockIdx.y;
  const int qbase = qb * BQ + wave * 32;

  // staging slot: thread t stages rows (srow, srow+32), key/col chunk scg
  const int srow = tid >> 3, scg = tid & 7;

  bf16x8 qf[2][2];
#pragma unroll
  for (int g = 0; g < 2; ++g)
#pragma unroll
    for (int c = 0; c < 2; ++c)
      qf[g][c] = *(const bf16x8*)(qp + (size_t)(qbase + g * 16 + l16) * AD +
                                  c * 32 + quad * 8);

  floatx4 o[2][4];
#pragma unroll
  for (int g = 0; g < 2; ++g)
#pragma unroll
    for (int nt = 0; nt < 4; ++nt)
      o[g][nt] = (floatx4){0.f, 0.f, 0.f, 0.f};
  float lsum[2] = {0.f, 0.f};

  // prologue: prefetch tile 0
  int kb0 = ks * KPB;
  bf16x8 kpre0 = *(const bf16x8*)(kp + (size_t)(kb0 + srow) * AD + scg * 8);
  bf16x8 kpre1 = *(const bf16x8*)(kp + (size_t)(kb0 + srow + 32) * AD + scg * 8);
  bf16x8 vpre0 = *(const bf16x8*)(vt + (size_t)srow * NK + kb0 + scg * 8);
  bf16x8 vpre1 = *(const bf16x8*)(vt + (size_t)(srow + 32) * NK + kb0 + scg * 8);

#pragma unroll
  for (int kt = 0; kt < TILES; ++kt) {
    const int keybase = ks * KPB + kt * BK;
    const int nb = ks * KPB + ((kt + 1) & (TILES - 1)) * BK;

    __syncthreads();  // previous tile fully consumed
    *(bf16x8*)&Kt[srow][scg * 8] = kpre0;
    *(bf16x8*)&Kt[srow + 32][scg * 8] = kpre1;
    *(bf16x8*)&Vts[srow][scg * 8] = vpre0;
    *(bf16x8*)&Vts[srow + 32][scg * 8] = vpre1;
    __syncthreads();

    // prefetch next K (covered by S+PV compute below)
    kpre0 = *(const bf16x8*)(kp + (size_t)(nb + srow) * AD + scg * 8);
    kpre1 = *(const bf16x8*)(kp + (size_t)(nb + srow + 32) * AD + scg * 8);

    // S^T = K.Q^T per 16-key subtile; exp + pack immediately
#pragma unroll
    for (int st = 0; st < 4; ++st) {
      bf16x8 ka0 = *(const bf16x8*)&Kt[st * 16 + l16][quad * 8];
      bf16x8 ka1 = *(const bf16x8*)&Kt[st * 16 + l16][quad * 8 + 32];
#pragma unroll
      for (int g = 0; g < 2; ++g) {
        floatx4 acc = {0.f, 0.f, 0.f, 0.f};
        acc = MFMA16(ka0, qf[g][0], acc);
        acc = MFMA16(ka1, qf[g][1], acc);
        float p0 = __builtin_amdgcn_exp2f(acc[0]);
        float p1 = __builtin_amdgcn_exp2f(acc[1]);
        float p2 = __builtin_amdgcn_exp2f(acc[2]);
        float p3 = __builtin_amdgcn_exp2f(acc[3]);
        lsum[g] += (p0 + p1) + (p2 + p3);
        bf16x4 pk = {(bf16)p0, (bf16)p1, (bf16)p2, (bf16)p3};
        *(bf16x4*)&Pt[wave][g * 16 + l16][st * 16 + quad * 4] = pk;
      }
    }

    // prefetch next V
    vpre0 = *(const bf16x8*)(vt + (size_t)srow * NK + nb + scg * 8);
    vpre1 = *(const bf16x8*)(vt + (size_t)(srow + 32) * NK + nb + scg * 8);

    // Pt is per-wave-private: compiler-inserted lgkmcnt orders write->read
    bf16x8 pf[2][2];
#pragma unroll
    for (int g = 0; g < 2; ++g)
#pragma unroll
      for (int c = 0; c < 2; ++c)
        pf[g][c] = *(const bf16x8*)&Pt[wave][g * 16 + l16][quad * 8 + c * 32];

#pragma unroll
    for (int nt = 0; nt < 4; ++nt) {
      bf16x8 vb0 = *(const bf16x8*)&Vts[nt * 16 + l16][quad * 8];
      bf16x8 vb1 = *(const bf16x8*)&Vts[nt * 16 + l16][quad * 8 + 32];
#pragma unroll
      for (int g = 0; g < 2; ++g) {
        o[g][nt] = MFMA16(pf[g][0], vb0, o[g][nt]);
        o[g][nt] = MFMA16(pf[g][1], vb1, o[g][nt]);
      }
    }
  }

#pragma unroll
  for (int g = 0; g < 2; ++g) {
    float t = lsum[g];
    t += __shfl_xor(t, 16, 64);
    t += __shfl_xor(t, 32, 64);
    lsum[g] = t;
  }

  bf16* ob = Opart + (size_t)ks * NQ * AD + (size_t)qbase * AD;
#pragma unroll
  for (int g = 0; g < 2; ++g)
#pragma unroll
    for (int nt = 0; nt < 4; ++nt)
#pragma unroll
      for (int r = 0; r < 4; ++r)
        ob[(size_t)(g * 16 + quad * 4 + r) * AD + nt * 16 + l16] =
            (bf16)o[g][nt][r];
  if (quad == 0) {
#pragma unroll
    for (int g = 0; g < 2; ++g)
      lpart[(size_t)ks * NQ + qbase + g * 16 + l16] = lsum[g];
  }
}

// ---------------- combine partials ------------------------------------------
__global__ __launch_bounds__(256) void combine_kernel(
    const bf16* __restrict__ Opart, const float* __restrict__ lpart,
    float* __restrict__ out) {
  int t = blockIdx.x * 256 + threadIdx.x;
  int gid = t * 4;
  int qrow = gid >> 6;
  float ls = 0.f;
#pragma unroll
  for (int s = 0; s < KSPLIT; ++s) ls += lpart[(size_t)s * NQ + qrow];
  float a0 = 0.f, a1 = 0.f, a2 = 0.f, a3 = 0.f;
#pragma unroll
  for (int s = 0; s < KSPLIT; ++s) {
    bf16x4 ov = *(const bf16x4*)(Opart + (size_t)s * NQ * AD + gid);
    a0 += (float)ov[0];
    a1 += (float)ov[1];
    a2 += (float)ov[2];
    a3 += (float)ov[3];
  }
  float inv = 1.0f / ls;
  float4 res = {a0 * inv, a1 * inv, a2 * inv, a3 * inv};
  *(float4*)(out + gid) = res;
}

// ---------------- launch -----------------------------------------------------
extern "C" void kernel_launch(void* const* d_in, const int* in_sizes, int n_in,
                              void* d_out, int out_size, void* d_ws,
                              size_t ws_size, hipStream_t stream) {
  const float* q = (const float*)d_in[0];
  const float* k = (const float*)d_in[1];
  const float* v = (const float*)d_in[2];
  const float* Wq = (const float*)d_in[3];
  const float* bq = (const float*)d_in[4];
  const float* Wk = (const float*)d_in[5];
  const float* bk = (const float*)d_in[6];
  const float* Wv = (const float*)d_in[7];
  const float* bv = (const float*)d_in[8];
  float* out = (float*)d_out;

  char* ws = (char*)d_ws;
  bf16* qout = (bf16*)(ws);                    // 512 KB
  bf16* kout = (bf16*)(ws + 524288);           // 1 MB
  bf16* vtout = (bf16*)(ws + 1572864);         // 1 MB
  bf16* Opart = (bf16*)(ws + 2621440);         // 32*4096*64*2 = 32 MB
  float* lpart = (float*)(ws + 2621440 + (size_t)KSPLIT * NQ * AD * 2);

  proj_mfma<<<320, 256, 0, stream>>>(q, k, v, Wq, bq, Wk, bk, Wv, bv, qout,
                                     kout, vtout);
  flash_kernel<<<dim3(KSPLIT, NQ / BQ), 256, 0, stream>>>(qout, kout, vtout,
                                                          Opart, lpart);
  combine_kernel<<<NQ * AD / 1024, 256, 0, stream>>>(Opart, lpart, out);
}